// Round 10
// baseline (40.253 us; speedup 1.0000x reference)
//
#include <hip/hip_runtime.h>

typedef _Float16 half8 __attribute__((ext_vector_type(8)));
typedef float f32x16 __attribute__((ext_vector_type(16)));

#define TPB 256   // 4 waves (known-good wave count from R4-R8)
#define NQ 4      // query groups (of 32) per wave -> 128 queries per block
#define GPW 64    // target groups per wave = 8192 / 32 / 4 waves

__device__ __forceinline__ float min3f(float a, float b, float c) {
    float d;
    asm("v_min3_f32 %0, %1, %2, %3" : "=v"(d) : "v"(a), "v"(b), "v"(c));
    return d;
}

// 8 independent running pairwise minima (depth-1 dependency per MFMA).
#define FOLD8(Dv, acc)                                  \
    acc[0] = min3f(Dv[0],  Dv[1],  acc[0]);             \
    acc[1] = min3f(Dv[2],  Dv[3],  acc[1]);             \
    acc[2] = min3f(Dv[4],  Dv[5],  acc[2]);             \
    acc[3] = min3f(Dv[6],  Dv[7],  acc[3]);             \
    acc[4] = min3f(Dv[8],  Dv[9],  acc[4]);             \
    acc[5] = min3f(Dv[10], Dv[11], acc[5]);             \
    acc[6] = min3f(Dv[12], Dv[13], acc[6]);             \
    acc[7] = min3f(Dv[14], Dv[15], acc[7]);

// Single fused kernel: no workspace, no prep, no memset, no atomics, one launch.
// block = 4 waves sharing 128 queries (NQ=4 groups); waves partition the 8192
// targets 4-way (GPW=64 groups each); LDS tree-reduce across waves; direct store.
// D = |t|^2 + |q|^2 - 2 q.t computed inside mfma_32x32x16_f16 via K-slot packing
// with hi/lo fp16 splits (fp32-grade precision; passing absmax ~1e-3 in R4-R8).
//  A (target row, lane half h): h0: xh xh xl yh yh yl zh zh | h1: zl sh sl 1 1 0 0 0
//  B (query col, lane half h):  h0: mxh mxl mxh myh myl myh mzh mzl | h1: mzh 1 1 sh sl 0 0 0
// (K-permutation-invariant as long as A and B use matching slot maps.)
__global__ void __launch_bounds__(TPB) cd_fused(
        const float* __restrict__ xyz1, const float* __restrict__ xyz2,
        float* __restrict__ out) {
    __shared__ float red[4][128];
    const int qt  = blockIdx.x;          // query tile of 128 (0..63)
    const int bd  = blockIdx.y;          // dir*4 + b
    const int dir = bd >> 2, b = bd & 3;
    const int l = threadIdx.x & 63, w = threadIdx.x >> 6;
    const int h = l >> 5;
    const int r32 = l & 31;
    const float* q = (dir ? xyz2 : xyz1) + (size_t)b * 8192 * 3;
    const float* t = (dir ? xyz1 : xyz2) + (size_t)b * 8192 * 3;
    const int qbase = qt * 128;

    const _Float16 one = (_Float16)1.0f, zero = (_Float16)0.0f;

    // ---- B-fragments (queries), built once per wave (same code as passing R8) ----
    half8 Bf[NQ];
    #pragma unroll
    for (int j = 0; j < NQ; ++j) {
        int qi = qbase + j * 32 + r32;
        float px = q[qi*3+0], py = q[qi*3+1], pz = q[qi*3+2];
        float mx = -2.f * px, my = -2.f * py, mz = -2.f * pz;
        float sq = __builtin_fmaf(px, px, __builtin_fmaf(py, py, pz * pz));
        _Float16 mxh = (_Float16)mx, mxl = (_Float16)(mx - (float)mxh);
        _Float16 myh = (_Float16)my, myl = (_Float16)(my - (float)myh);
        _Float16 mzh = (_Float16)mz, mzl = (_Float16)(mz - (float)mzh);
        _Float16 sh  = (_Float16)sq, sl  = (_Float16)(sq - (float)sh);
        half8 f;
        if (h == 0) { f[0]=mxh; f[1]=mxl; f[2]=mxh; f[3]=myh; f[4]=myl; f[5]=myh; f[6]=mzh; f[7]=mzl; }
        else        { f[0]=mzh; f[1]=one; f[2]=one; f[3]=sh; f[4]=sl; f[5]=zero; f[6]=zero; f[7]=zero; }
        Bf[j] = f;
    }

    f32x16 Z;
    #pragma unroll
    for (int i = 0; i < 16; ++i) Z[i] = 0.f;

    float b8[NQ][8];
    #pragma unroll
    for (int j = 0; j < NQ; ++j)
        #pragma unroll
        for (int p = 0; p < 8; ++p) b8[j][p] = 3.0e38f;

    // ---- main loop: wave w owns target groups w*GPW .. w*GPW+GPW-1 ----
    // A-fragment built in registers, prep's exact if/else form (R9's ternary
    // form failed; this isolates that variable).
    const float* tw = t + ((size_t)(w * GPW) * 32 + r32) * 3;
    #pragma unroll 2
    for (int g = 0; g < GPW; ++g) {
        const float* tp = tw + (size_t)g * 96;
        float x = tp[0], y = tp[1], z = tp[2];
        float sq = __builtin_fmaf(x, x, __builtin_fmaf(y, y, z * z));
        _Float16 xh = (_Float16)x, xl = (_Float16)(x - (float)xh);
        _Float16 yh = (_Float16)y, yl = (_Float16)(y - (float)yh);
        _Float16 zh = (_Float16)z, zl = (_Float16)(z - (float)zh);
        _Float16 sh = (_Float16)sq, sl = (_Float16)(sq - (float)sh);
        half8 a;
        if (h == 0) {
            a[0]=xh; a[1]=xh; a[2]=xl; a[3]=yh; a[4]=yh; a[5]=yl; a[6]=zh; a[7]=zh;
        } else {
            a[0]=zl; a[1]=sh; a[2]=sl; a[3]=one; a[4]=one; a[5]=zero; a[6]=zero; a[7]=zero;
        }

        #pragma unroll
        for (int j = 0; j < NQ; ++j) {
            f32x16 D = __builtin_amdgcn_mfma_f32_32x32x16_f16(a, Bf[j], Z, 0, 0, 0);
            FOLD8(D, b8[j]);
        }
    }

    // ---- fold 8 -> 1 per j, cross-half, then cross-wave via LDS ----
    float best[NQ];
    #pragma unroll
    for (int j = 0; j < NQ; ++j) {
        float m01 = fminf(b8[j][0], b8[j][1]);
        float m23 = fminf(b8[j][2], b8[j][3]);
        float m45 = fminf(b8[j][4], b8[j][5]);
        float m67 = fminf(b8[j][6], b8[j][7]);
        best[j] = fminf(fminf(m01, m23), fminf(m45, m67));
    }
    #pragma unroll
    for (int j = 0; j < NQ; ++j) {
        float o = __shfl_xor(best[j], 32, 64);
        best[j] = fminf(best[j], o);
    }
    if (l < 32) {
        #pragma unroll
        for (int j = 0; j < NQ; ++j) red[w][j * 32 + l] = best[j];
    }
    __syncthreads();
    if (threadIdx.x < 128) {
        int ti = threadIdx.x;
        float m = fminf(fminf(red[0][ti], red[1][ti]), fminf(red[2][ti], red[3][ti]));
        out[(size_t)dir * 32768 + (size_t)b * 8192 + qbase + ti] = m;
    }
}

extern "C" void kernel_launch(void* const* d_in, const int* in_sizes, int n_in,
                              void* d_out, int out_size, void* d_ws, size_t ws_size,
                              hipStream_t stream) {
    const float* xyz1 = (const float*)d_in[0];
    const float* xyz2 = (const float*)d_in[1];

    dim3 grid(64, 8);   // query tiles (128 q) x (dir*4+b)
    cd_fused<<<grid, TPB, 0, stream>>>(xyz1, xyz2, (float*)d_out);
}

// Round 11
// 36.185 us; speedup vs baseline: 1.1124x; 1.1124x over previous
//
#include <hip/hip_runtime.h>

typedef _Float16 half8 __attribute__((ext_vector_type(8)));
typedef float f32x16 __attribute__((ext_vector_type(16)));

#define TPB 256   // 4 waves (known-good; 512 silently failed in R9)
#define NQ 4      // query groups (of 32) per wave -> 128 queries per block
#define TS 4      // target slices: block covers 2048 targets
#define GPW 16    // target groups per wave = 2048 / 32 / 4 waves

__device__ __forceinline__ float min3f(float a, float b, float c) {
    float d;
    asm("v_min3_f32 %0, %1, %2, %3" : "=v"(d) : "v"(a), "v"(b), "v"(c));
    return d;
}

// 8 independent running pairwise minima (depth-1 dependency per MFMA).
#define FOLD8(Dv, acc)                                  \
    acc[0] = min3f(Dv[0],  Dv[1],  acc[0]);             \
    acc[1] = min3f(Dv[2],  Dv[3],  acc[1]);             \
    acc[2] = min3f(Dv[4],  Dv[5],  acc[2]);             \
    acc[3] = min3f(Dv[6],  Dv[7],  acc[3]);             \
    acc[4] = min3f(Dv[8],  Dv[9],  acc[4]);             \
    acc[5] = min3f(Dv[10], Dv[11], acc[5]);             \
    acc[6] = min3f(Dv[12], Dv[13], acc[6]);             \
    acc[7] = min3f(Dv[14], Dv[15], acc[7]);

// Stage 1: identical math/structure to passing R10, but target dim split TS ways
// across blocks (grid 512 -> 2048, occupancy cap 25% -> 100%). Partial min per
// (query, slice) written to ws[gq*4+ts]; no atomics, no init needed.
// D = |t|^2 + |q|^2 - 2 q.t inside mfma_32x32x16_f16 via K-slot packing with
// hi/lo fp16 splits.
//  A (target row, half h): h0: xh xh xl yh yh yl zh zh | h1: zl sh sl 1 1 0 0 0
//  B (query col, half h):  h0: mxh mxl mxh myh myl myh mzh mzl | h1: mzh 1 1 sh sl 0 0 0
__global__ void __launch_bounds__(TPB) cd_partial(
        const float* __restrict__ xyz1, const float* __restrict__ xyz2,
        float* __restrict__ ws) {
    __shared__ float red[4][128];
    const int ts  = blockIdx.x;          // target slice (0..TS-1)
    const int qt  = blockIdx.y;          // query tile of 128 (0..63)
    const int bd  = blockIdx.z;          // dir*4 + b
    const int dir = bd >> 2, b = bd & 3;
    const int l = threadIdx.x & 63, w = threadIdx.x >> 6;
    const int h = l >> 5;
    const int r32 = l & 31;
    const float* q = (dir ? xyz2 : xyz1) + (size_t)b * 8192 * 3;
    const float* t = (dir ? xyz1 : xyz2) + (size_t)b * 8192 * 3;
    const int qbase = qt * 128;

    const _Float16 one = (_Float16)1.0f, zero = (_Float16)0.0f;

    // ---- B-fragments (queries), built once per wave ----
    half8 Bf[NQ];
    #pragma unroll
    for (int j = 0; j < NQ; ++j) {
        int qi = qbase + j * 32 + r32;
        float px = q[qi*3+0], py = q[qi*3+1], pz = q[qi*3+2];
        float mx = -2.f * px, my = -2.f * py, mz = -2.f * pz;
        float sq = __builtin_fmaf(px, px, __builtin_fmaf(py, py, pz * pz));
        _Float16 mxh = (_Float16)mx, mxl = (_Float16)(mx - (float)mxh);
        _Float16 myh = (_Float16)my, myl = (_Float16)(my - (float)myh);
        _Float16 mzh = (_Float16)mz, mzl = (_Float16)(mz - (float)mzh);
        _Float16 sh  = (_Float16)sq, sl  = (_Float16)(sq - (float)sh);
        half8 f;
        if (h == 0) { f[0]=mxh; f[1]=mxl; f[2]=mxh; f[3]=myh; f[4]=myl; f[5]=myh; f[6]=mzh; f[7]=mzl; }
        else        { f[0]=mzh; f[1]=one; f[2]=one; f[3]=sh; f[4]=sl; f[5]=zero; f[6]=zero; f[7]=zero; }
        Bf[j] = f;
    }

    f32x16 Z;
    #pragma unroll
    for (int i = 0; i < 16; ++i) Z[i] = 0.f;

    float b8[NQ][8];
    #pragma unroll
    for (int j = 0; j < NQ; ++j)
        #pragma unroll
        for (int p = 0; p < 8; ++p) b8[j][p] = 3.0e38f;

    // ---- main loop: this block's slice = targets [ts*2048, (ts+1)*2048);
    //      wave w owns groups w*GPW .. w*GPW+GPW-1 within the slice ----
    const float* tw = t + ((size_t)(ts * 2048) + (size_t)(w * GPW) * 32 + r32) * 3;
    #pragma unroll 2
    for (int g = 0; g < GPW; ++g) {
        const float* tp = tw + (size_t)g * 96;
        float x = tp[0], y = tp[1], z = tp[2];
        float sq = __builtin_fmaf(x, x, __builtin_fmaf(y, y, z * z));
        _Float16 xh = (_Float16)x, xl = (_Float16)(x - (float)xh);
        _Float16 yh = (_Float16)y, yl = (_Float16)(y - (float)yh);
        _Float16 zh = (_Float16)z, zl = (_Float16)(z - (float)zh);
        _Float16 sh = (_Float16)sq, sl = (_Float16)(sq - (float)sh);
        half8 a;
        if (h == 0) {
            a[0]=xh; a[1]=xh; a[2]=xl; a[3]=yh; a[4]=yh; a[5]=yl; a[6]=zh; a[7]=zh;
        } else {
            a[0]=zl; a[1]=sh; a[2]=sl; a[3]=one; a[4]=one; a[5]=zero; a[6]=zero; a[7]=zero;
        }

        #pragma unroll
        for (int j = 0; j < NQ; ++j) {
            f32x16 D = __builtin_amdgcn_mfma_f32_32x32x16_f16(a, Bf[j], Z, 0, 0, 0);
            FOLD8(D, b8[j]);
        }
    }

    // ---- fold 8 -> 1 per j, cross-half, then cross-wave via LDS ----
    float best[NQ];
    #pragma unroll
    for (int j = 0; j < NQ; ++j) {
        float m01 = fminf(b8[j][0], b8[j][1]);
        float m23 = fminf(b8[j][2], b8[j][3]);
        float m45 = fminf(b8[j][4], b8[j][5]);
        float m67 = fminf(b8[j][6], b8[j][7]);
        best[j] = fminf(fminf(m01, m23), fminf(m45, m67));
    }
    #pragma unroll
    for (int j = 0; j < NQ; ++j) {
        float o = __shfl_xor(best[j], 32, 64);
        best[j] = fminf(best[j], o);
    }
    if (l < 32) {
        #pragma unroll
        for (int j = 0; j < NQ; ++j) red[w][j * 32 + l] = best[j];
    }
    __syncthreads();
    if (threadIdx.x < 128) {
        int ti = threadIdx.x;
        float m = fminf(fminf(red[0][ti], red[1][ti]), fminf(red[2][ti], red[3][ti]));
        // gq = bd*8192 + qbase + ti  (== output index); partials at [gq][TS]
        ws[((size_t)bd * 8192 + qbase + ti) * TS + ts] = m;
    }
}

// Stage 2: out[gq] = min over TS partials. One float4 read per thread (coalesced).
__global__ void __launch_bounds__(256) cd_reduce(
        const float* __restrict__ ws, float* __restrict__ out) {
    int i = blockIdx.x * 256 + threadIdx.x;   // 0 .. 65535
    float4 p = ((const float4*)ws)[i];
    out[i] = fminf(fminf(p.x, p.y), fminf(p.z, p.w));
}

extern "C" void kernel_launch(void* const* d_in, const int* in_sizes, int n_in,
                              void* d_out, int out_size, void* d_ws, size_t ws_size,
                              hipStream_t stream) {
    const float* xyz1 = (const float*)d_in[0];
    const float* xyz2 = (const float*)d_in[1];
    float* ws = (float*)d_ws;   // 1 MB partials, written before read each call

    dim3 grid(TS, 64, 8);   // target slices x query tiles (128 q) x (dir*4+b)
    cd_partial<<<grid, TPB, 0, stream>>>(xyz1, xyz2, ws);

    cd_reduce<<<dim3(out_size / 256), 256, 0, stream>>>(ws, (float*)d_out);
}